// Round 2
// baseline (2295.455 us; speedup 1.0000x reference)
//
#include <hip/hip_runtime.h>
#include <cstddef>

// Problem constants (from reference)
#define NN 100000
#define NE 1600000
#define NH 5
#define NC 12
#define HC 60     // NH*NC
#define FN 128
#define FE 32
#define HID 16
#define NCLS 2

typedef float v4f __attribute__((ext_vector_type(4)));

#if __has_builtin(__builtin_amdgcn_exp2f)
#define EXP2F(x) __builtin_amdgcn_exp2f(x)
#else
#define EXP2F(x) exp2f(x)
#endif

__device__ __forceinline__ float bperm(int idxb, float x) {
    return __int_as_float(__builtin_amdgcn_ds_bpermute(idxb, __float_as_int(x)));
}

// ---------------------------------------------------------------------------
// qkvs: q,k,v,skip = X @ W? + b?  for 4 matrices [DIN,60].
// Block = 16 nodes in LDS; thread = 4 cols x 4 nodes register tile
// (operand reads per FMA: 0.5 vs 1.1 in the old 1x8 layout).
// k and v are written PACKED into kvb[node][120] (k: 0..59, v: 60..119)
// so agg's per-edge gather hits one contiguous 480B region.
// ---------------------------------------------------------------------------
template<int DIN>
__global__ __launch_bounds__(256) void qkvs_kernel(
    const float* __restrict__ X,
    const float* __restrict__ Wq, const float* __restrict__ bq,
    const float* __restrict__ Wk, const float* __restrict__ bk,
    const float* __restrict__ Wv, const float* __restrict__ bv,
    const float* __restrict__ Ws, const float* __restrict__ bs,
    float* __restrict__ qb, float* __restrict__ kvb, float* __restrict__ sb)
{
    constexpr int NB = 16;
    __shared__ float xs[NB][DIN + 5];          // +5 pad: conflict-free reads
    const int n0 = blockIdx.x * NB;            // NN == 16*6250 exactly
    for (int i = threadIdx.x; i < NB * DIN; i += 256) {
        const int nd = i / DIN, r = i - nd * DIN;
        xs[nd][r] = X[(size_t)(n0 + nd) * DIN + r];
    }
    __syncthreads();

    const int t = threadIdx.x;
    if (t >= 240) return;
    const int cg = t % 60, ng = t / 60;        // col-quad, node-group
    const int mat = cg / 15, q4 = (cg % 15) * 4;
    const float* W; const float* b; float* outp; int ostr;
    switch (mat) {
        case 0:  W = Wq; b = bq; outp = qb;       ostr = 60;  break;
        case 1:  W = Wk; b = bk; outp = kvb;      ostr = 120; break;
        case 2:  W = Wv; b = bv; outp = kvb + 60; ostr = 120; break;
        default: W = Ws; b = bs; outp = sb;       ostr = 60;  break;
    }
    float acc[4][4] = {};
    #pragma unroll 2
    for (int r = 0; r < DIN; ++r) {
        const float4 w = *(const float4*)(W + r * 60 + q4);
        #pragma unroll
        for (int j = 0; j < 4; ++j) {
            const float xv = xs[4 * ng + j][r];
            acc[j][0] = fmaf(xv, w.x, acc[j][0]);
            acc[j][1] = fmaf(xv, w.y, acc[j][1]);
            acc[j][2] = fmaf(xv, w.z, acc[j][2]);
            acc[j][3] = fmaf(xv, w.w, acc[j][3]);
        }
    }
    const float4 bb = *(const float4*)(b + q4);
    #pragma unroll
    for (int j = 0; j < 4; ++j) {
        float4 o;
        o.x = acc[j][0] + bb.x; o.y = acc[j][1] + bb.y;
        o.z = acc[j][2] + bb.z; o.w = acc[j][3] + bb.w;
        *(float4*)(outp + (size_t)(n0 + 4 * ng + j) * ostr + q4) = o;
    }
}

// ---------------------------------------------------------------------------
// CSR build: histogram of dst -> exclusive scan -> scatter (+eaP copy fused)
// ---------------------------------------------------------------------------
__global__ __launch_bounds__(256) void hist_kernel(
    const int* __restrict__ ei, int* __restrict__ cnt)
{
    const int e = blockIdx.x * 256 + threadIdx.x;
    if (e < NE) atomicAdd(&cnt[ei[NE + e]], 1);
}

__global__ __launch_bounds__(1024) void scan1_kernel(
    const int* __restrict__ cnt, int* __restrict__ excl, int* __restrict__ bsum)
{
    __shared__ int sh[1024];
    const int i = blockIdx.x * 1024 + threadIdx.x;
    const int v = (i < NN) ? cnt[i] : 0;
    sh[threadIdx.x] = v;
    __syncthreads();
    for (int off = 1; off < 1024; off <<= 1) {
        const int t = (threadIdx.x >= off) ? sh[threadIdx.x - off] : 0;
        __syncthreads();
        sh[threadIdx.x] += t;
        __syncthreads();
    }
    if (i < NN) excl[i] = sh[threadIdx.x] - v;     // block-local exclusive
    if (threadIdx.x == 1023) bsum[blockIdx.x] = sh[1023];
}

// parallel block-sum scan (was a 1-thread 98-iter dependent-load loop)
__global__ __launch_bounds__(128) void scan2_kernel(
    int* __restrict__ bsum, int nb, int* __restrict__ start)
{
    __shared__ int sh[128];
    const int i = threadIdx.x;
    const int v = (i < nb) ? bsum[i] : 0;
    sh[i] = v;
    __syncthreads();
    for (int off = 1; off < 128; off <<= 1) {
        const int tv = (i >= off) ? sh[i - off] : 0;
        __syncthreads();
        sh[i] += tv;
        __syncthreads();
    }
    if (i < nb) bsum[i] = sh[i] - v;      // exclusive
    if (i == 127) start[NN] = sh[127];    // total == NE
}

__global__ __launch_bounds__(1024) void scan3_kernel(
    int* __restrict__ start, const int* __restrict__ bsum)
{
    const int i = blockIdx.x * 1024 + threadIdx.x;
    if (i < NN) start[i] += bsum[blockIdx.x];
}

// scatter with fused eaP build: eaP[pos] = ea[e] row (nt load + nt store so
// the 205 MB stream doesn't churn L2/L3). perm only needed for !lin fallback.
__global__ __launch_bounds__(256) void scatter_kernel(
    const int* __restrict__ ei, int* __restrict__ cursor,
    int* __restrict__ perm, int* __restrict__ srcs,
    const float* __restrict__ ea, float* __restrict__ eaP, const int do_ea)
{
    const int e = blockIdx.x * 256 + threadIdx.x;
    if (e >= NE) return;
    const int d = ei[NE + e];
    const int pos = atomicAdd(&cursor[d], 1);
    srcs[pos] = ei[e];
    if (do_ea) {
        const v4f* s4 = (const v4f*)(ea + (size_t)e * FE);
        v4f* d4 = (v4f*)(eaP + (size_t)pos * FE);
        #pragma unroll
        for (int i = 0; i < 8; ++i)
            __builtin_nontemporal_store(__builtin_nontemporal_load(s4 + i), d4 + i);
    } else {
        perm[pos] = e;
    }
}

// ---------------------------------------------------------------------------
// Aggregation: one wave per dst node, lane = channel hc.
// - srcs[t]/start[] at uniform addresses -> s_load (no readlane machinery)
// - eaP rows: per-lane NONTEMPORAL vector loads (div0 = divergent-typed zero
//   blocks scalarization, which would silently drop the nt bit). Keeps the
//   205 MB stream out of L3 so the 48 MB packed k/v stays L3-resident.
// - packed kv rows: k at +0, v at +60 (same DRAM page per edge).
// - per-head reduce: depth-2, 5 ds_bpermute with precomputed byte indices.
// - exp via v_exp_f32 (exp2 with rescaled constants; softmax-normalized).
// ---------------------------------------------------------------------------
template<bool LIN>
__global__ __launch_bounds__(256) void agg_kernel(
    const int* __restrict__ perm, const int* __restrict__ srcs,
    const int* __restrict__ start,
    const float* __restrict__ ea, const float* __restrict__ We,
    const float* __restrict__ q, const float* __restrict__ kv,
    const float* __restrict__ sk, float* __restrict__ hout)
{
    const int wv    = threadIdx.x >> 6;
    const int lane  = threadIdx.x & 63;
    const int n     = blockIdx.x * 4 + wv;
    const int hc    = (lane < 60) ? lane : 0;
    const int hd    = hc / NC;          // head 0..4
    const int hbase = hd * NC;
    const int c     = hc - hbase;       // channel within head, 0..11

    // byte indices for the two-stage reduce (stage1: +3,+6,+9 mod 12;
    // stage2: the other two residues mod 3)
    const int i1 = (hbase + (c + 3) % 12) << 2;
    const int i2 = (hbase + (c + 6) % 12) << 2;
    const int i3 = (hbase + (c + 9) % 12) << 2;
    const int j1 = (hbase + (c + 1) % 3) << 2;
    const int j2 = (hbase + (c + 2) % 3) << 2;

    const int div0 = (int)__builtin_amdgcn_mbcnt_lo(0u, 0u);  // == 0, divergent-typed

    float Wcol[FE];
    #pragma unroll
    for (int r = 0; r < FE; ++r) Wcol[r] = We[r * 60 + hc];

    const float qv = q[(size_t)n * 60 + hc];
    const float sv = sk[(size_t)n * 60 + hc];

    const int s0 = __builtin_amdgcn_readfirstlane(start[n]);
    const int s1 = __builtin_amdgcn_readfirstlane(start[n + 1]);

    float acc = 0.f, den = 0.f;

    auto load_ea = [&](v4f (&E)[8], int tt) {
        const v4f* er;
        if (LIN) er = (const v4f*)(ea + (size_t)tt * FE) + div0;
        else     er = (const v4f*)(ea + (size_t)perm[tt] * FE) + div0;
        #pragma unroll
        for (int i = 0; i < 8; ++i) E[i] = __builtin_nontemporal_load(er + i);
    };

    auto compute = [&](const v4f (&E)[8], float KV, float VV) {
        float e0 = 0.f, e1 = 0.f, e2 = 0.f, e3 = 0.f;
        #pragma unroll
        for (int i = 0; i < 8; ++i) {
            e0 = fmaf(E[i].x, Wcol[4 * i + 0], e0);
            e1 = fmaf(E[i].y, Wcol[4 * i + 1], e1);
            e2 = fmaf(E[i].z, Wcol[4 * i + 2], e2);
            e3 = fmaf(E[i].w, Wcol[4 * i + 3], e3);
        }
        const float eacc = (e0 + e1) + (e2 + e3);
        const float p = qv * (KV + eacc);
        const float f = (p + bperm(i1, p)) + (bperm(i2, p) + bperm(i3, p));
        const float a = (f + bperm(j1, f)) + bperm(j2, f);
        // exp(a/sqrt(12) - 20) == exp2(a * log2e/sqrt(12) - 20*log2e)
        const float w = EXP2F(fmaf(a, 0.41647013f, -28.8539009f));
        acc = fmaf(w, VV + eacc, acc);
        den += w;
    };

    v4f eaA[8], eaB[8];
    float kA = 0.f, vA = 0.f, kB = 0.f, vB = 0.f;
    float kC = 0.f, vC = 0.f, kD = 0.f, vD = 0.f;

    if (s0 < s1) {
        {   // prologue
            const int sa = srcs[s0];
            kA = kv[(size_t)sa * 120 + hc];
            vA = kv[(size_t)sa * 120 + 60 + hc];
            if (s0 + 1 < s1) {
                const int sb_ = srcs[s0 + 1];
                kB = kv[(size_t)sb_ * 120 + hc];
                vB = kv[(size_t)sb_ * 120 + 60 + hc];
            }
            load_ea(eaA, s0);
        }
        for (int t = s0; t < s1; t += 2) {
            if (t + 1 < s1) load_ea(eaB, t + 1);
            if (t + 2 < s1) {
                const int sc_ = srcs[t + 2];
                kC = kv[(size_t)sc_ * 120 + hc];
                vC = kv[(size_t)sc_ * 120 + 60 + hc];
            }
            compute(eaA, kA, vA);
            if (t + 2 < s1) load_ea(eaA, t + 2);
            if (t + 3 < s1) {
                const int sd_ = srcs[t + 3];
                kD = kv[(size_t)sd_ * 120 + hc];
                vD = kv[(size_t)sd_ * 120 + 60 + hc];
            }
            if (t + 1 < s1) compute(eaB, kB, vB);
            kA = kC; vA = vC; kB = kD; vB = vD;
        }
    }

    if (lane < 60)
        hout[(size_t)n * 60 + hc] = fmaxf(acc / (den + 1e-16f) + sv, 0.f);
}

// ---------------------------------------------------------------------------
// MLP head: out = relu(h @ W1 + b1) @ W2 + b2     (one thread per node)
// ---------------------------------------------------------------------------
__global__ __launch_bounds__(256) void mlp_kernel(
    const float* __restrict__ h,
    const float* __restrict__ W1, const float* __restrict__ b1,
    const float* __restrict__ W2, const float* __restrict__ b2,
    float* __restrict__ out)
{
    __shared__ float sW1[60 * HID];
    __shared__ float sb1[HID];
    __shared__ float sW2[HID * NCLS];
    __shared__ float sb2[NCLS];
    for (int i = threadIdx.x; i < 60 * HID; i += 256) sW1[i] = W1[i];
    if (threadIdx.x < HID)        sb1[threadIdx.x] = b1[threadIdx.x];
    if (threadIdx.x < HID * NCLS) sW2[threadIdx.x] = W2[threadIdx.x];
    if (threadIdx.x < NCLS)       sb2[threadIdx.x] = b2[threadIdx.x];
    __syncthreads();

    const int n = blockIdx.x * 256 + threadIdx.x;
    if (n >= NN) return;
    const float* __restrict__ hr = h + (size_t)n * 60;
    float hv[60];
    #pragma unroll
    for (int i = 0; i < 15; ++i) {
        const float4 t = ((const float4*)hr)[i];
        hv[4 * i + 0] = t.x; hv[4 * i + 1] = t.y;
        hv[4 * i + 2] = t.z; hv[4 * i + 3] = t.w;
    }
    float o0 = sb2[0], o1 = sb2[1];
    for (int j = 0; j < HID; ++j) {
        float t = sb1[j];
        #pragma unroll
        for (int i = 0; i < 60; ++i) t = fmaf(hv[i], sW1[i * HID + j], t);
        t = fmaxf(t, 0.f);
        o0 = fmaf(t, sW2[2 * j + 0], o0);
        o1 = fmaf(t, sW2[2 * j + 1], o1);
    }
    out[(size_t)n * 2 + 0] = o0;
    out[(size_t)n * 2 + 1] = o1;
}

// ---------------------------------------------------------------------------
extern "C" void kernel_launch(void* const* d_in, const int* in_sizes, int n_in,
                              void* d_out, int out_size, void* d_ws, size_t ws_size,
                              hipStream_t stream)
{
    const float* x   = (const float*)d_in[0];
    const int*   ei  = (const int*)  d_in[1];
    const float* ea  = (const float*)d_in[2];
    const float* Wq1 = (const float*)d_in[3];  const float* bq1 = (const float*)d_in[4];
    const float* Wk1 = (const float*)d_in[5];  const float* bk1 = (const float*)d_in[6];
    const float* Wv1 = (const float*)d_in[7];  const float* bv1 = (const float*)d_in[8];
    const float* We1 = (const float*)d_in[9];
    const float* Ws1 = (const float*)d_in[10]; const float* bs1 = (const float*)d_in[11];
    const float* Wq2 = (const float*)d_in[12]; const float* bq2 = (const float*)d_in[13];
    const float* Wk2 = (const float*)d_in[14]; const float* bk2 = (const float*)d_in[15];
    const float* Wv2 = (const float*)d_in[16]; const float* bv2 = (const float*)d_in[17];
    const float* We2 = (const float*)d_in[18];
    const float* Ws2 = (const float*)d_in[19]; const float* bs2 = (const float*)d_in[20];
    const float* W1  = (const float*)d_in[21]; const float* b1  = (const float*)d_in[22];
    const float* W2  = (const float*)d_in[23]; const float* b2  = (const float*)d_in[24];
    float* out = (float*)d_out;

    // workspace: [ints][pad->256B][qb | kvb(2x) | sb | h0][eaP NE*32]
    int* cnt    = (int*)d_ws;             // NN
    int* startp = cnt + NN;               // NN+1
    int* cursor = startp + NN + 1;        // NN
    int* bsum   = cursor + NN;            // 128
    int* perm   = bsum + 128;             // NE (fallback only)
    int* srcs   = perm + NE;              // NE
    const size_t int_bytes = (size_t)(3 * NN + 1 + 128 + 2 * NE) * sizeof(int);
    const size_t f_off = (int_bytes + 255) & ~(size_t)255;
    const size_t NHC = (size_t)NN * 60;
    float* qb  = (float*)((char*)d_ws + f_off);
    float* kvb = qb + NHC;                // NN*120 packed k|v
    float* sb  = kvb + 2 * NHC;
    float* h0  = sb + NHC;                // layer1 out; overwritten by layer2 out
    float* eaP = h0 + NHC;                // NE*32 (CSR-ordered edge_attr)
    const size_t need = f_off + 5 * NHC * sizeof(float) + (size_t)NE * FE * sizeof(float);
    const bool lin = ws_size >= need;

    const int qkvs_blocks = NN / 16;               // 6250 exact
    const int e256_blocks = NE / 256;              // 6250 exact
    const int scan_blocks = (NN + 1023) / 1024;    // 98
    const int agg_blocks  = NN / 4;                // 25000 exact
    const int mlp_blocks  = (NN + 255) / 256;      // 391

    // ---- CSR build (once, shared by both layers) ----
    hipMemsetAsync(cnt, 0, (size_t)NN * sizeof(int), stream);
    hist_kernel<<<e256_blocks, 256, 0, stream>>>(ei, cnt);
    scan1_kernel<<<scan_blocks, 1024, 0, stream>>>(cnt, startp, bsum);
    scan2_kernel<<<1, 128, 0, stream>>>(bsum, scan_blocks, startp);
    scan3_kernel<<<scan_blocks, 1024, 0, stream>>>(startp, bsum);
    hipMemcpyAsync(cursor, startp, (size_t)NN * sizeof(int),
                   hipMemcpyDeviceToDevice, stream);
    scatter_kernel<<<e256_blocks, 256, 0, stream>>>(
        ei, cursor, perm, srcs, ea, eaP, lin ? 1 : 0);

    // ---- layer 1 ----
    qkvs_kernel<FN><<<qkvs_blocks, 256, 0, stream>>>(
        x, Wq1, bq1, Wk1, bk1, Wv1, bv1, Ws1, bs1, qb, kvb, sb);
    if (lin)
        agg_kernel<true><<<agg_blocks, 256, 0, stream>>>(
            perm, srcs, startp, eaP, We1, qb, kvb, sb, h0);
    else
        agg_kernel<false><<<agg_blocks, 256, 0, stream>>>(
            perm, srcs, startp, ea, We1, qb, kvb, sb, h0);

    // ---- layer 2 ----
    qkvs_kernel<HC><<<qkvs_blocks, 256, 0, stream>>>(
        h0, Wq2, bq2, Wk2, bk2, Wv2, bv2, Ws2, bs2, qb, kvb, sb);
    if (lin)
        agg_kernel<true><<<agg_blocks, 256, 0, stream>>>(
            perm, srcs, startp, eaP, We2, qb, kvb, sb, h0);
    else
        agg_kernel<false><<<agg_blocks, 256, 0, stream>>>(
            perm, srcs, startp, ea, We2, qb, kvb, sb, h0);   // h0 reuse is safe

    // ---- MLP head ----
    mlp_kernel<<<mlp_blocks, 256, 0, stream>>>(h0, W1, b1, W2, b2, out);
}

// Round 3
// 1183.619 us; speedup vs baseline: 1.9394x; 1.9394x over previous
//
#include <hip/hip_runtime.h>
#include <cstddef>

// Problem constants (from reference)
#define NN 100000
#define NE 1600000
#define NH 5
#define NC 12
#define HC 60     // NH*NC
#define FN 128
#define FE 32
#define HID 16
#define NCLS 2

typedef float v4f __attribute__((ext_vector_type(4)));
typedef _Float16 h2 __attribute__((ext_vector_type(2)));
typedef _Float16 h8 __attribute__((ext_vector_type(8)));

#if __has_builtin(__builtin_amdgcn_exp2f)
#define EXP2F(x) __builtin_amdgcn_exp2f(x)
#else
#define EXP2F(x) exp2f(x)
#endif

__device__ __forceinline__ float bperm(int idxb, float x) {
    return __int_as_float(__builtin_amdgcn_ds_bpermute(idxb, __float_as_int(x)));
}

// half2 dot with f32 accumulate: v_dot2_f32_f16 when available
__device__ __forceinline__ float dot2h(unsigned int u, h2 w, float c) {
    const h2 a = __builtin_bit_cast(h2, u);
#if __has_builtin(__builtin_amdgcn_fdot2)
    return __builtin_amdgcn_fdot2(a, w, c, false);
#else
    return fmaf((float)a[0], (float)w[0], fmaf((float)a[1], (float)w[1], c));
#endif
}

// ---------------------------------------------------------------------------
// qkvs: q,k,v,skip = X @ W? + b?  for 4 matrices [DIN,60].
// Block = 16 nodes in LDS; thread = 4 cols x 4 nodes register tile.
// k and v are written PACKED into kvb[node][120] (k: 0..59, v: 60..119)
// so agg's per-edge gather hits one contiguous 480B region.
// ---------------------------------------------------------------------------
template<int DIN>
__global__ __launch_bounds__(256) void qkvs_kernel(
    const float* __restrict__ X,
    const float* __restrict__ Wq, const float* __restrict__ bq,
    const float* __restrict__ Wk, const float* __restrict__ bk,
    const float* __restrict__ Wv, const float* __restrict__ bv,
    const float* __restrict__ Ws, const float* __restrict__ bs,
    float* __restrict__ qb, float* __restrict__ kvb, float* __restrict__ sb)
{
    constexpr int NB = 16;
    __shared__ float xs[NB][DIN + 5];          // +5 pad: conflict-free reads
    const int n0 = blockIdx.x * NB;            // NN == 16*6250 exactly
    for (int i = threadIdx.x; i < NB * DIN; i += 256) {
        const int nd = i / DIN, r = i - nd * DIN;
        xs[nd][r] = X[(size_t)(n0 + nd) * DIN + r];
    }
    __syncthreads();

    const int t = threadIdx.x;
    if (t >= 240) return;
    const int cg = t % 60, ng = t / 60;        // col-quad, node-group
    const int mat = cg / 15, q4 = (cg % 15) * 4;
    const float* W; const float* b; float* outp; int ostr;
    switch (mat) {
        case 0:  W = Wq; b = bq; outp = qb;       ostr = 60;  break;
        case 1:  W = Wk; b = bk; outp = kvb;      ostr = 120; break;
        case 2:  W = Wv; b = bv; outp = kvb + 60; ostr = 120; break;
        default: W = Ws; b = bs; outp = sb;       ostr = 60;  break;
    }
    float acc[4][4] = {};
    #pragma unroll 2
    for (int r = 0; r < DIN; ++r) {
        const float4 w = *(const float4*)(W + r * 60 + q4);
        #pragma unroll
        for (int j = 0; j < 4; ++j) {
            const float xv = xs[4 * ng + j][r];
            acc[j][0] = fmaf(xv, w.x, acc[j][0]);
            acc[j][1] = fmaf(xv, w.y, acc[j][1]);
            acc[j][2] = fmaf(xv, w.z, acc[j][2]);
            acc[j][3] = fmaf(xv, w.w, acc[j][3]);
        }
    }
    const float4 bb = *(const float4*)(b + q4);
    #pragma unroll
    for (int j = 0; j < 4; ++j) {
        float4 o;
        o.x = acc[j][0] + bb.x; o.y = acc[j][1] + bb.y;
        o.z = acc[j][2] + bb.z; o.w = acc[j][3] + bb.w;
        *(float4*)(outp + (size_t)(n0 + 4 * ng + j) * ostr + q4) = o;
    }
}

// ---------------------------------------------------------------------------
// CSR build: histogram of dst -> exclusive scan -> scatter edge ids (+src ids)
// ---------------------------------------------------------------------------
__global__ __launch_bounds__(256) void hist_kernel(
    const int* __restrict__ ei, int* __restrict__ cnt)
{
    const int e = blockIdx.x * 256 + threadIdx.x;
    if (e < NE) atomicAdd(&cnt[ei[NE + e]], 1);
}

__global__ __launch_bounds__(1024) void scan1_kernel(
    const int* __restrict__ cnt, int* __restrict__ excl, int* __restrict__ bsum)
{
    __shared__ int sh[1024];
    const int i = blockIdx.x * 1024 + threadIdx.x;
    const int v = (i < NN) ? cnt[i] : 0;
    sh[threadIdx.x] = v;
    __syncthreads();
    for (int off = 1; off < 1024; off <<= 1) {
        const int t = (threadIdx.x >= off) ? sh[threadIdx.x - off] : 0;
        __syncthreads();
        sh[threadIdx.x] += t;
        __syncthreads();
    }
    if (i < NN) excl[i] = sh[threadIdx.x] - v;     // block-local exclusive
    if (threadIdx.x == 1023) bsum[blockIdx.x] = sh[1023];
}

// parallel block-sum scan (128 threads >= 98 blocks)
__global__ __launch_bounds__(128) void scan2_kernel(
    int* __restrict__ bsum, int nb, int* __restrict__ start)
{
    __shared__ int sh[128];
    const int i = threadIdx.x;
    const int v = (i < nb) ? bsum[i] : 0;
    sh[i] = v;
    __syncthreads();
    for (int off = 1; off < 128; off <<= 1) {
        const int tv = (i >= off) ? sh[i - off] : 0;
        __syncthreads();
        sh[i] += tv;
        __syncthreads();
    }
    if (i < nb) bsum[i] = sh[i] - v;      // exclusive
    if (i == 127) start[NN] = sh[127];    // total == NE
}

__global__ __launch_bounds__(1024) void scan3_kernel(
    int* __restrict__ start, const int* __restrict__ bsum)
{
    const int i = blockIdx.x * 1024 + threadIdx.x;
    if (i < NN) start[i] += bsum[blockIdx.x];
}

// scatter: perm + srcs only (4B scattered writes — cheap). eaP build is NOT
// fused here: scattered 128B row writes caused 4x write amplification (r2).
__global__ __launch_bounds__(256) void scatter_kernel(
    const int* __restrict__ ei, int* __restrict__ cursor,
    int* __restrict__ perm, int* __restrict__ srcs)
{
    const int e = blockIdx.x * 256 + threadIdx.x;
    if (e >= NE) return;
    const int d = ei[NE + e];
    const int pos = atomicAdd(&cursor[d], 1);
    perm[pos] = e;
    srcs[pos] = ei[e];
}

// ---------------------------------------------------------------------------
// permea: eaPh[slot] = fp16(ea[perm[slot]])  (CSR order, half precision).
// Gather-read is row-coalesced (4 threads cover one 128B row); write is
// position-linear (16B/thread) -> fully coalesced. fp16 halves agg's eaP
// stream (205->102 MB) so the agg working set fits in the 256MB L3 and the
// packed k/v stays resident.
// ---------------------------------------------------------------------------
__global__ __launch_bounds__(256) void permea_kernel(
    const int* __restrict__ perm, const float* __restrict__ ea,
    h8* __restrict__ eaPh)
{
    const int t = blockIdx.x * 256 + threadIdx.x;   // NE*4 threads
    const int slot = t >> 2, part = t & 3;
    const int e = perm[slot];
    const float4* src = (const float4*)(ea + (size_t)e * FE) + 2 * part;
    const float4 a = src[0];
    const float4 b = src[1];
    h8 o;
    o[0] = (_Float16)a.x; o[1] = (_Float16)a.y;
    o[2] = (_Float16)a.z; o[3] = (_Float16)a.w;
    o[4] = (_Float16)b.x; o[5] = (_Float16)b.y;
    o[6] = (_Float16)b.z; o[7] = (_Float16)b.w;
    eaPh[(size_t)slot * 4 + part] = o;
}

// ---------------------------------------------------------------------------
// Aggregation: one wave per dst node, lane = channel hc.
// - start[]/srcs[t]/eaPh rows at wave-uniform addresses -> s_load pipeline
// - eaPh row = 64B = 4x s_load_dwordx4 into SGPRs; dot via v_dot2_f32_f16
//   against an fp16 We column (f32 accumulate)
// - packed kv rows: k at +0, v at +60 (one contiguous 480B gather per edge)
// - per-head reduce: depth-2, 5 ds_bpermute with precomputed byte indices
// - exp via v_exp_f32 (exp2 with rescaled constants; softmax-normalized)
// ---------------------------------------------------------------------------
template<bool LIN>
__global__ __launch_bounds__(256) void agg_kernel(
    const int* __restrict__ perm, const int* __restrict__ srcs,
    const int* __restrict__ start,
    const _Float16* __restrict__ eaH, const float* __restrict__ eaF,
    const float* __restrict__ We,
    const float* __restrict__ q, const float* __restrict__ kv,
    const float* __restrict__ sk, float* __restrict__ hout)
{
    const int wv    = threadIdx.x >> 6;
    const int lane  = threadIdx.x & 63;
    const int n     = blockIdx.x * 4 + wv;
    const int hc    = (lane < 60) ? lane : 0;
    const int hd    = hc / NC;          // head 0..4
    const int hbase = hd * NC;
    const int c     = hc - hbase;       // channel within head, 0..11

    // byte indices for the two-stage reduce
    const int i1 = (hbase + (c + 3) % 12) << 2;
    const int i2 = (hbase + (c + 6) % 12) << 2;
    const int i3 = (hbase + (c + 9) % 12) << 2;
    const int j1 = (hbase + (c + 1) % 3) << 2;
    const int j2 = (hbase + (c + 2) % 3) << 2;

    const float qv = q[(size_t)n * 60 + hc];
    const float sv = sk[(size_t)n * 60 + hc];

    const int s0 = __builtin_amdgcn_readfirstlane(start[n]);
    const int s1 = __builtin_amdgcn_readfirstlane(start[n + 1]);

    float acc = 0.f, den = 0.f;

    auto tail = [&](float eacc, float KV, float VV) {
        const float p = qv * (KV + eacc);
        const float f = (p + bperm(i1, p)) + (bperm(i2, p) + bperm(i3, p));
        const float a = (f + bperm(j1, f)) + bperm(j2, f);
        // exp(a/sqrt(12) - 20) == exp2(a * log2e/sqrt(12) - 20*log2e)
        const float w = EXP2F(fmaf(a, 0.41647013f, -28.8539009f));
        acc = fmaf(w, VV + eacc, acc);
        den += w;
    };

    if constexpr (LIN) {
        h2 WH[16];                              // fp16 We column, 16 half2
        #pragma unroll
        for (int p = 0; p < 16; ++p) {
            h2 w;
            w[0] = (_Float16)We[(2 * p)     * 60 + hc];
            w[1] = (_Float16)We[(2 * p + 1) * 60 + hc];
            WH[p] = w;
        }

        auto load_ea = [&](uint4 (&E)[4], int tt) {
            const uint4* er = (const uint4*)(eaH + (size_t)tt * FE);  // 64B row
            #pragma unroll
            for (int i = 0; i < 4; ++i) E[i] = er[i];
        };
        auto compute = [&](const uint4 (&E)[4], float KV, float VV) {
            float d0 = 0.f, d1 = 0.f;
            #pragma unroll
            for (int i = 0; i < 4; ++i) {
                d0 = dot2h(E[i].x, WH[4 * i + 0], d0);
                d1 = dot2h(E[i].y, WH[4 * i + 1], d1);
                d0 = dot2h(E[i].z, WH[4 * i + 2], d0);
                d1 = dot2h(E[i].w, WH[4 * i + 3], d1);
            }
            tail(d0 + d1, KV, VV);
        };

        uint4 eaA[4], eaB[4];
        float kA = 0.f, vA = 0.f, kB = 0.f, vB = 0.f;
        float kC = 0.f, vC = 0.f, kD = 0.f, vD = 0.f;

        if (s0 < s1) {
            {   // prologue
                const int sa = srcs[s0];
                kA = kv[(size_t)sa * 120 + hc];
                vA = kv[(size_t)sa * 120 + 60 + hc];
                if (s0 + 1 < s1) {
                    const int sb_ = srcs[s0 + 1];
                    kB = kv[(size_t)sb_ * 120 + hc];
                    vB = kv[(size_t)sb_ * 120 + 60 + hc];
                }
                load_ea(eaA, s0);
            }
            for (int t = s0; t < s1; t += 2) {
                if (t + 1 < s1) load_ea(eaB, t + 1);
                if (t + 2 < s1) {
                    const int sc_ = srcs[t + 2];
                    kC = kv[(size_t)sc_ * 120 + hc];
                    vC = kv[(size_t)sc_ * 120 + 60 + hc];
                }
                compute(eaA, kA, vA);
                if (t + 2 < s1) load_ea(eaA, t + 2);
                if (t + 3 < s1) {
                    const int sd_ = srcs[t + 3];
                    kD = kv[(size_t)sd_ * 120 + hc];
                    vD = kv[(size_t)sd_ * 120 + 60 + hc];
                }
                if (t + 1 < s1) compute(eaB, kB, vB);
                kA = kC; vA = vC; kB = kD; vB = vD;
            }
        }
    } else {
        // fallback (workspace too small): f32, perm-indexed, unpipelined
        float Wcol[FE];
        #pragma unroll
        for (int r = 0; r < FE; ++r) Wcol[r] = We[r * 60 + hc];
        for (int t = s0; t < s1; ++t) {
            const int e = perm[t];
            const float* __restrict__ er = eaF + (size_t)e * FE;
            float e0 = 0.f, e1 = 0.f;
            #pragma unroll
            for (int r = 0; r < FE; r += 2) {
                e0 = fmaf(er[r],     Wcol[r],     e0);
                e1 = fmaf(er[r + 1], Wcol[r + 1], e1);
            }
            const int sa = srcs[t];
            const float KV = kv[(size_t)sa * 120 + hc];
            const float VV = kv[(size_t)sa * 120 + 60 + hc];
            tail(e0 + e1, KV, VV);
        }
    }

    if (lane < 60)
        hout[(size_t)n * 60 + hc] = fmaxf(acc / (den + 1e-16f) + sv, 0.f);
}

// ---------------------------------------------------------------------------
// MLP head: out = relu(h @ W1 + b1) @ W2 + b2     (one thread per node)
// ---------------------------------------------------------------------------
__global__ __launch_bounds__(256) void mlp_kernel(
    const float* __restrict__ h,
    const float* __restrict__ W1, const float* __restrict__ b1,
    const float* __restrict__ W2, const float* __restrict__ b2,
    float* __restrict__ out)
{
    __shared__ float sW1[60 * HID];
    __shared__ float sb1[HID];
    __shared__ float sW2[HID * NCLS];
    __shared__ float sb2[NCLS];
    for (int i = threadIdx.x; i < 60 * HID; i += 256) sW1[i] = W1[i];
    if (threadIdx.x < HID)        sb1[threadIdx.x] = b1[threadIdx.x];
    if (threadIdx.x < HID * NCLS) sW2[threadIdx.x] = W2[threadIdx.x];
    if (threadIdx.x < NCLS)       sb2[threadIdx.x] = b2[threadIdx.x];
    __syncthreads();

    const int n = blockIdx.x * 256 + threadIdx.x;
    if (n >= NN) return;
    const float* __restrict__ hr = h + (size_t)n * 60;
    float hv[60];
    #pragma unroll
    for (int i = 0; i < 15; ++i) {
        const float4 t = ((const float4*)hr)[i];
        hv[4 * i + 0] = t.x; hv[4 * i + 1] = t.y;
        hv[4 * i + 2] = t.z; hv[4 * i + 3] = t.w;
    }
    float o0 = sb2[0], o1 = sb2[1];
    for (int j = 0; j < HID; ++j) {
        float t = sb1[j];
        #pragma unroll
        for (int i = 0; i < 60; ++i) t = fmaf(hv[i], sW1[i * HID + j], t);
        t = fmaxf(t, 0.f);
        o0 = fmaf(t, sW2[2 * j + 0], o0);
        o1 = fmaf(t, sW2[2 * j + 1], o1);
    }
    out[(size_t)n * 2 + 0] = o0;
    out[(size_t)n * 2 + 1] = o1;
}

// ---------------------------------------------------------------------------
extern "C" void kernel_launch(void* const* d_in, const int* in_sizes, int n_in,
                              void* d_out, int out_size, void* d_ws, size_t ws_size,
                              hipStream_t stream)
{
    const float* x   = (const float*)d_in[0];
    const int*   ei  = (const int*)  d_in[1];
    const float* ea  = (const float*)d_in[2];
    const float* Wq1 = (const float*)d_in[3];  const float* bq1 = (const float*)d_in[4];
    const float* Wk1 = (const float*)d_in[5];  const float* bk1 = (const float*)d_in[6];
    const float* Wv1 = (const float*)d_in[7];  const float* bv1 = (const float*)d_in[8];
    const float* We1 = (const float*)d_in[9];
    const float* Ws1 = (const float*)d_in[10]; const float* bs1 = (const float*)d_in[11];
    const float* Wq2 = (const float*)d_in[12]; const float* bq2 = (const float*)d_in[13];
    const float* Wk2 = (const float*)d_in[14]; const float* bk2 = (const float*)d_in[15];
    const float* Wv2 = (const float*)d_in[16]; const float* bv2 = (const float*)d_in[17];
    const float* We2 = (const float*)d_in[18];
    const float* Ws2 = (const float*)d_in[19]; const float* bs2 = (const float*)d_in[20];
    const float* W1  = (const float*)d_in[21]; const float* b1  = (const float*)d_in[22];
    const float* W2  = (const float*)d_in[23]; const float* b2  = (const float*)d_in[24];
    float* out = (float*)d_out;

    // workspace: [ints][pad->256B][qb | kvb(2x) | sb | h0][eaPh NE*32 halves]
    int* cnt    = (int*)d_ws;             // NN
    int* startp = cnt + NN;               // NN+1
    int* cursor = startp + NN + 1;        // NN
    int* bsum   = cursor + NN;            // 128
    int* perm   = bsum + 128;             // NE
    int* srcs   = perm + NE;              // NE
    const size_t int_bytes = (size_t)(3 * NN + 1 + 128 + 2 * NE) * sizeof(int);
    const size_t f_off = (int_bytes + 255) & ~(size_t)255;
    const size_t NHC = (size_t)NN * 60;
    float* qb  = (float*)((char*)d_ws + f_off);
    float* kvb = qb + NHC;                // NN*120 packed k|v
    float* sb  = kvb + 2 * NHC;
    float* h0  = sb + NHC;                // layer1 out; overwritten by layer2 out
    _Float16* eaPh = (_Float16*)(h0 + NHC);   // NE*32 halves (CSR-ordered)
    const size_t need = f_off + 5 * NHC * sizeof(float)
                      + (size_t)NE * FE * sizeof(_Float16);
    const bool lin = ws_size >= need;

    const int qkvs_blocks = NN / 16;               // 6250 exact
    const int e256_blocks = NE / 256;              // 6250 exact
    const int scan_blocks = (NN + 1023) / 1024;    // 98
    const int agg_blocks  = NN / 4;                // 25000 exact
    const int mlp_blocks  = (NN + 255) / 256;      // 391
    const int perm_blocks = NE * 4 / 256;          // 25000 exact

    // ---- CSR build (once, shared by both layers) ----
    hipMemsetAsync(cnt, 0, (size_t)NN * sizeof(int), stream);
    hist_kernel<<<e256_blocks, 256, 0, stream>>>(ei, cnt);
    scan1_kernel<<<scan_blocks, 1024, 0, stream>>>(cnt, startp, bsum);
    scan2_kernel<<<1, 128, 0, stream>>>(bsum, scan_blocks, startp);
    scan3_kernel<<<scan_blocks, 1024, 0, stream>>>(startp, bsum);
    hipMemcpyAsync(cursor, startp, (size_t)NN * sizeof(int),
                   hipMemcpyDeviceToDevice, stream);
    scatter_kernel<<<e256_blocks, 256, 0, stream>>>(ei, cursor, perm, srcs);
    if (lin)
        permea_kernel<<<perm_blocks, 256, 0, stream>>>(perm, ea, (h8*)eaPh);

    // ---- layer 1 ----
    qkvs_kernel<FN><<<qkvs_blocks, 256, 0, stream>>>(
        x, Wq1, bq1, Wk1, bk1, Wv1, bv1, Ws1, bs1, qb, kvb, sb);
    if (lin)
        agg_kernel<true><<<agg_blocks, 256, 0, stream>>>(
            perm, srcs, startp, eaPh, ea, We1, qb, kvb, sb, h0);
    else
        agg_kernel<false><<<agg_blocks, 256, 0, stream>>>(
            perm, srcs, startp, eaPh, ea, We1, qb, kvb, sb, h0);

    // ---- layer 2 ----
    qkvs_kernel<HC><<<qkvs_blocks, 256, 0, stream>>>(
        h0, Wq2, bq2, Wk2, bk2, Wv2, bv2, Ws2, bs2, qb, kvb, sb);
    if (lin)
        agg_kernel<true><<<agg_blocks, 256, 0, stream>>>(
            perm, srcs, startp, eaPh, ea, We2, qb, kvb, sb, h0);
    else
        agg_kernel<false><<<agg_blocks, 256, 0, stream>>>(
            perm, srcs, startp, eaPh, ea, We2, qb, kvb, sb, h0);   // h0 reuse safe

    // ---- MLP head ----
    mlp_kernel<<<mlp_blocks, 256, 0, stream>>>(h0, W1, b1, W2, b2, out);
}